// Round 1
// 190.655 us; speedup vs baseline: 1.5807x; 1.5807x over previous
//
#include <hip/hip_runtime.h>
#include <hip/hip_bf16.h>

#define N_ROWS 8192
#define DIM 512
#define SCALE 2.659f
#define MAXLOGIT 2.659f
#define NCHUNK 8
#define CHUNK 1024
#define BM 128
#define BN 128

typedef __attribute__((ext_vector_type(8))) short short8;
typedef __attribute__((ext_vector_type(4))) float f32x4;

__device__ __forceinline__ unsigned short f2bf(float f) {
    unsigned int u = __float_as_uint(f);
    u += 0x7fffu + ((u >> 16) & 1u);
    return (unsigned short)(u >> 16);
}

// ---------------------------------------------------------------- normalize
// Also zero-initializes rowsum/colsum accumulators (128 KB) and out[0].
__global__ __launch_bounds__(256) void norm_cast_kernel(
    const float* __restrict__ text, const float* __restrict__ image,
    unsigned short* __restrict__ imgn, unsigned short* __restrict__ txtn,
    float4* __restrict__ zbase, float* __restrict__ out)
{
    if (blockIdx.x < 32) {
        zbase[blockIdx.x * 256 + threadIdx.x] = make_float4(0.f, 0.f, 0.f, 0.f);
        if (blockIdx.x == 0 && threadIdx.x == 0) out[0] = 0.f;
    }
    int row  = blockIdx.x * 4 + (threadIdx.x >> 6);
    int lane = threadIdx.x & 63;
    const float* src;
    unsigned short* dst;
    if (row < N_ROWS) { src = image + (size_t)row * DIM; dst = imgn + (size_t)row * DIM; }
    else { int r = row - N_ROWS; src = text + (size_t)r * DIM; dst = txtn + (size_t)r * DIM; }
    const float4* s4 = (const float4*)src + lane * 2;
    float4 a = s4[0], b = s4[1];
    float ss = a.x*a.x + a.y*a.y + a.z*a.z + a.w*a.w
             + b.x*b.x + b.y*b.y + b.z*b.z + b.w*b.w;
    #pragma unroll
    for (int m = 1; m < 64; m <<= 1) ss += __shfl_xor(ss, m, 64);
    float sc = 1.0f / fmaxf(sqrtf(ss), 1e-12f);
    uint4 o;
    o.x = (unsigned)f2bf(a.x*sc) | ((unsigned)f2bf(a.y*sc) << 16);
    o.y = (unsigned)f2bf(a.z*sc) | ((unsigned)f2bf(a.w*sc) << 16);
    o.z = (unsigned)f2bf(b.x*sc) | ((unsigned)f2bf(b.y*sc) << 16);
    o.w = (unsigned)f2bf(b.z*sc) | ((unsigned)f2bf(b.w*sc) << 16);
    *((uint4*)dst + lane) = o;
}

// ---------------------------------------------------------------- fused GEMM
// Computes S = scale*(img @ txt^T) ONCE. Row stats feed the image-direction
// loss; column stats feed the text-direction loss (S^T rows = S cols, target
// matrix is symmetric). Halves MFMA/LDS/fetch vs. the two-direction version.
#define ASYNC16(gp, lp) \
  __builtin_amdgcn_global_load_lds((const __attribute__((address_space(1))) void*)(gp), \
                                   (__attribute__((address_space(3))) void*)(lp), 16, 0, 0)

__global__ __launch_bounds__(256, 2) void gemm_fused_kernel(
    const unsigned short* __restrict__ imgn, const unsigned short* __restrict__ txtn,
    const int* __restrict__ labels,
    float* __restrict__ rowsum, float* __restrict__ colsum)
{
    __shared__ unsigned short Ald[BM * 32];
    __shared__ unsigned short Bld[BN * 32];
    __shared__ float red[2][BM][2];
    __shared__ float colb[2][CHUNK][2];   // [wr][col-in-chunk][{s,d}]

    int bid    = blockIdx.x;
    int rowblk = bid & 63;
    int chunk  = bid >> 6;
    const unsigned short* A = imgn;
    const unsigned short* B = txtn;
    int rowBase  = rowblk * BM;
    int colBase0 = chunk * CHUNK;

    int tid  = threadIdx.x;
    int lane = tid & 63;
    int w    = tid >> 6;
    int wr   = w >> 1, wc = w & 1;
    int q    = lane >> 4;
    int lm   = lane & 15;

    // zero the column accumulator (2*CHUNK*2 floats = 1024 float4)
    {
        float4* cb4 = (float4*)colb;
        #pragma unroll
        for (int i = 0; i < 4; ++i)
            cb4[tid + i * 256] = make_float4(0.f, 0.f, 0.f, 0.f);
    }

    // this lane's 16 accumulator rows: rowQ + mi*16 + r
    int rowQ = rowBase + wr * 64 + q * 4;
    int labR[16];
    #pragma unroll
    for (int mi = 0; mi < 4; ++mi)
      #pragma unroll
      for (int r = 0; r < 4; ++r)
        labR[mi*4 + r] = labels[rowQ + mi*16 + r];

    float s_acc[16], d_acc[16];
    #pragma unroll
    for (int i = 0; i < 16; ++i) { s_acc[i] = 0.f; d_acc[i] = 0.f; }

    int srow  = lane >> 2;        // staging: row within 16-row group
    int spart = (lane & 3) * 8;   // staging: k offset (elems)

    for (int tile = 0; tile < CHUNK / BN; ++tile) {
        int colBase = colBase0 + tile * BN;
        f32x4 acc[4][4];
        #pragma unroll
        for (int mi = 0; mi < 4; ++mi)
          #pragma unroll
          for (int ni = 0; ni < 4; ++ni)
            acc[mi][ni] = (f32x4){0.f, 0.f, 0.f, 0.f};

        for (int kt = 0; kt < DIM / 32; ++kt) {
            int k0 = kt * 32;
            __syncthreads();   // all waves done reading LDS before re-stage
            #pragma unroll
            for (int i = 0; i < 2; ++i) {
                int rlocal = i*64 + w*16 + srow;
                ASYNC16(A + (size_t)(rowBase + rlocal) * DIM + k0 + spart,
                        Ald + (i*64 + w*16) * 32);
                ASYNC16(B + (size_t)(colBase + rlocal) * DIM + k0 + spart,
                        Bld + (i*64 + w*16) * 32);
            }
            __syncthreads();   // drains vmcnt(0): staging complete

            short8 af[4], bf[4];
            #pragma unroll
            for (int mi = 0; mi < 4; ++mi)
                af[mi] = *(const short8*)(Ald + (wr*64 + mi*16 + lm)*32 + q*8);
            #pragma unroll
            for (int ni = 0; ni < 4; ++ni)
                bf[ni] = *(const short8*)(Bld + (wc*64 + ni*16 + lm)*32 + q*8);
            #pragma unroll
            for (int mi = 0; mi < 4; ++mi)
              #pragma unroll
              for (int ni = 0; ni < 4; ++ni)
                acc[mi][ni] = __builtin_amdgcn_mfma_f32_16x16x32_bf16(
                                  af[mi], bf[ni], acc[mi][ni], 0, 0, 0);
        }

        // epilogue: one exp per S element serves BOTH loss directions.
        float cs[4], cd[4];
        #pragma unroll
        for (int ni = 0; ni < 4; ++ni) { cs[ni] = 0.f; cd[ni] = 0.f; }
        #pragma unroll
        for (int ni = 0; ni < 4; ++ni) {
            int j    = colBase + wc*64 + ni*16 + lm;
            int labj = labels[j];
            #pragma unroll
            for (int mi = 0; mi < 4; ++mi) {
              #pragma unroll
              for (int r = 0; r < 4; ++r) {
                int   idx = mi*4 + r;
                float v   = SCALE * acc[mi][ni][r];
                float e   = __expf(v - MAXLOGIT);
                bool  t = ((rowQ + mi*16 + r) == j) |
                          ((labj == labR[idx]) & (labR[idx] != -1));
                float dv = t ? v : 0.0f;
                s_acc[idx] += e;
                d_acc[idx] += dv;
                cs[ni] += e;       // column (text-direction) partials
                cd[ni] += dv;
              }
            }
        }
        // reduce column partials over the 4 q-groups (lane bits 4,5);
        // then q==0 lanes RMW their wave's private colb slot (race-free:
        // wr selects the slot, wc/ni/lm select disjoint columns).
        #pragma unroll
        for (int ni = 0; ni < 4; ++ni) {
            float s = cs[ni], d = cd[ni];
            s += __shfl_xor(s, 16, 64); d += __shfl_xor(d, 16, 64);
            s += __shfl_xor(s, 32, 64); d += __shfl_xor(d, 32, 64);
            if (q == 0) {
                int cidx = tile*BN + wc*64 + ni*16 + lm;
                colb[wr][cidx][0] += s;
                colb[wr][cidx][1] += d;
            }
        }
    }

    // row stats: reduce across the 16 column-lanes (low 4 lane bits)
    #pragma unroll
    for (int idx = 0; idx < 16; ++idx) {
        float s = s_acc[idx], d = d_acc[idx];
        #pragma unroll
        for (int m = 1; m < 16; m <<= 1) {
            s += __shfl_xor(s, m, 64);
            d += __shfl_xor(d, m, 64);
        }
        s_acc[idx] = s; d_acc[idx] = d;
    }
    if (lm == 0) {
        #pragma unroll
        for (int idx = 0; idx < 16; ++idx) {
            int rl = wr*64 + (idx>>2)*16 + q*4 + (idx&3);
            red[wc][rl][0] = s_acc[idx];
            red[wc][rl][1] = d_acc[idx];
        }
    }
    __syncthreads();
    if (tid < BM) {
        float s = red[0][tid][0] + red[1][tid][0];
        float d = red[0][tid][1] + red[1][tid][1];
        unsafeAtomicAdd(&rowsum[2*(rowBase + tid)],     s);
        unsafeAtomicAdd(&rowsum[2*(rowBase + tid) + 1], d);
    }
    // column stats: combine the two wr slots, flush to global accumulator
    for (int c = tid; c < CHUNK; c += 256) {
        float s = colb[0][c][0] + colb[1][c][0];
        float d = colb[0][c][1] + colb[1][c][1];
        unsafeAtomicAdd(&colsum[2*(colBase0 + c)],     s);
        unsafeAtomicAdd(&colsum[2*(colBase0 + c) + 1], d);
    }
}

// ---------------------------------------------------------------- final merge
__global__ __launch_bounds__(256) void loss_reduce_kernel(
    const int* __restrict__ labels, const float* __restrict__ rowsum,
    const float* __restrict__ colsum, float* __restrict__ out)
{
    __shared__ int   hist[128];
    __shared__ float wsum[4];
    int tid = threadIdx.x;
    if (tid < 128) hist[tid] = 0;
    __syncthreads();
    for (int i = tid; i < N_ROWS; i += 256) {
        int lb = labels[i];
        if (lb >= 0) atomicAdd(&hist[lb], 1);
    }
    __syncthreads();
    int i = blockIdx.x * 128 + (tid & 127);
    const float* src = (tid >> 7) ? colsum : rowsum;
    float s = src[2*i], d = src[2*i + 1];
    int lb = labels[i];
    float sT = (lb < 0) ? 1.0f : (float)hist[lb];
    float local = (MAXLOGIT + logf(s)) - d / sT;
    #pragma unroll
    for (int m = 1; m < 64; m <<= 1) local += __shfl_xor(local, m, 64);
    if ((tid & 63) == 0) wsum[tid >> 6] = local;
    __syncthreads();
    if (tid == 0)
        unsafeAtomicAdd(out, (wsum[0] + wsum[1] + wsum[2] + wsum[3])
                             * (1.0f / (2 * N_ROWS)));
}

// ---------------------------------------------------------------- launch
extern "C" void kernel_launch(void* const* d_in, const int* in_sizes, int n_in,
                              void* d_out, int out_size, void* d_ws, size_t ws_size,
                              hipStream_t stream)
{
    const float* text  = (const float*)d_in[0];
    const float* image = (const float*)d_in[1];
    const int*   labels = (const int*)d_in[2];

    unsigned short* imgn = (unsigned short*)d_ws;
    unsigned short* txtn = imgn + (size_t)N_ROWS * DIM;
    float* rowsum = (float*)((char*)d_ws + 2 * (size_t)N_ROWS * DIM * sizeof(unsigned short));
    float* colsum = rowsum + 2 * N_ROWS;
    float* out = (float*)d_out;

    hipLaunchKernelGGL(norm_cast_kernel, dim3(2 * N_ROWS / 4), dim3(256), 0, stream,
                       text, image, imgn, txtn, (float4*)rowsum, out);
    hipLaunchKernelGGL(gemm_fused_kernel, dim3(64 * NCHUNK), dim3(256), 0, stream,
                       imgn, txtn, labels, rowsum, colsum);
    hipLaunchKernelGGL(loss_reduce_kernel, dim3(64), dim3(256), 0, stream,
                       labels, rowsum, colsum, out);
}